// Round 9
// baseline (822.792 us; speedup 1.0000x reference)
//
#include <hip/hip_runtime.h>
#include <hip/hip_bf16.h>

#define M_TOKENS 4096
#define K_IN     4096
#define N_OUT    11008

#define BM 256
#define BN 256
#define BK 64
#define KTILES (K_IN / BK)   // 64

typedef __bf16 bf16x8 __attribute__((ext_vector_type(8)));
typedef float  f32x4  __attribute__((ext_vector_type(4)));

__device__ __forceinline__ void async_copy16(const void* g, void* l) {
    __builtin_amdgcn_global_load_lds(
        (const __attribute__((address_space(1))) void*)g,
        (__attribute__((address_space(3))) void*)l, 16, 0, 0);
}

// ---- x fp32 -> bf16 cast, 8 elems/thread ----
__global__ __launch_bounds__(256) void cast_x_kernel(const float* __restrict__ x,
                                                     __hip_bfloat16* __restrict__ xb) {
    size_t idx = (size_t)blockIdx.x * 256 + threadIdx.x;
    const float4* xf = reinterpret_cast<const float4*>(x) + idx * 2;
    float4 a = xf[0], b = xf[1];
    float v[8] = {a.x, a.y, a.z, a.w, b.x, b.y, b.z, b.w};
    alignas(16) __hip_bfloat16 t[8];
#pragma unroll
    for (int j = 0; j < 8; ++j) t[j] = __float2bfloat16(v[j]);
    *reinterpret_cast<uint4*>(xb + idx * 8) = *reinterpret_cast<const uint4*>(t);
}

// ---- int4-code dequant: wq[n,k] int32 -> wb[n,k] bf16 (B^T layout), 8 k/thread ----
__global__ __launch_bounds__(256) void dequant_kernel(const int* __restrict__ wq,
                                                      const float* __restrict__ snz,
                                                      __hip_bfloat16* __restrict__ wb) {
    size_t idx = (size_t)blockIdx.x * 256 + threadIdx.x;   // n*(K/8) + k8
    int n  = (int)(idx >> 9);         // K_IN/8 = 512
    int k8 = (int)(idx & 511);
    int g  = k8 >> 4;                 // (k8*8)/128
    const float* sz = snz + ((size_t)g * N_OUT + n) * 2;
    float scale = sz[0], zero = sz[1];
    const int4* q4 = reinterpret_cast<const int4*>(wq + (size_t)n * K_IN + (size_t)k8 * 8);
    int4 qa = q4[0], qb = q4[1];
    int q[8] = {qa.x, qa.y, qa.z, qa.w, qb.x, qb.y, qb.z, qb.w};
    alignas(16) __hip_bfloat16 t[8];
#pragma unroll
    for (int j = 0; j < 8; ++j)
        t[j] = __float2bfloat16((float)(q[j] - 8) * scale + zero);
    *reinterpret_cast<uint4*>(wb + idx * 8) = *reinterpret_cast<const uint4*>(t);
}

// ====== 256x256 bf16 GEMM — no-adjacency 4-phase pipeline ======
// Revised model (fits all 6 prior rounds): co-SIMD waves' reads interleave in
// the LDS FIFO -> no stagger -> read-wait and MFMA fully serialize whenever a
// phase consumes reads it issued. This schedule has NO read consumed in its
// issue phase (except 4-read bA, unavoidable). Consumption order per tile:
//   ph1: aL x bA   ph2: aL x bB   ph3: aH x bB   ph4: aH x bA
// Reads: ph1: bA<-CB(4)  ph2: aH<-CA(8)  ph3: aL'<-NA(8)  ph4: bB'<-NB(4).
// WAR retirement (single-buffered frags, 96 VGPR): aL' written ph3 after aL's
// last use ph2; bB' ph4 after ph3; bA'/aH' written next tile after ph4. OK.
// Sync per tile: vmcnt(0)+barrier mid-ph3 (stages issued ph1, ~2 phases old;
// wait-then-barrier invariant); bare barrier at end (every CA/CB read was
// consumed by an MFMA whose lgkm-wait completed pre-barrier -> safe to
// re-stage CA/CB after it). Counted lgkm only where a consuming MFMA could
// otherwise outrun a read: ph1 LGKM(0) [waits bA], ph3 LGKM(8) [waits aH,
// leaves aL' in flight]. ph2/ph4 have no waits at all (operands 1+ phase old;
// compiler data-deps + its own precise waitcnts protect correctness).

#define SCB()  __builtin_amdgcn_sched_barrier(0)
#define LGKM0() { asm volatile("s_waitcnt lgkmcnt(0)" ::: "memory"); SCB(); }
#define LGKM8() { asm volatile("s_waitcnt lgkmcnt(8)" ::: "memory"); SCB(); }
#define VM0BAR() { SCB(); asm volatile("s_waitcnt vmcnt(0)" ::: "memory"); \
                   __builtin_amdgcn_s_barrier(); SCB(); }
#define ENDBAR() { SCB(); __builtin_amdgcn_s_barrier(); SCB(); }

#define RD_AL(T) \
    _Pragma("unroll") for (int mi = 0; mi < 4; ++mi) \
    _Pragma("unroll") for (int kk = 0; kk < 2; ++kk) aL[mi][kk] = readA(T, mi, kk);
#define RD_AH(T) \
    _Pragma("unroll") for (int mi = 0; mi < 4; ++mi) \
    _Pragma("unroll") for (int kk = 0; kk < 2; ++kk) aH[mi][kk] = readA(T, 4 + mi, kk);
#define RD_BA(T) \
    _Pragma("unroll") for (int ni = 0; ni < 2; ++ni) \
    _Pragma("unroll") for (int kk = 0; kk < 2; ++kk) bA[ni][kk] = readB(T, ni, kk);
#define RD_BB(T) \
    _Pragma("unroll") for (int ni = 0; ni < 2; ++ni) \
    _Pragma("unroll") for (int kk = 0; kk < 2; ++kk) bB[ni][kk] = readB(T, 2 + ni, kk);

#define MFMA16(AOFF, AF, BF, NIB) \
    __builtin_amdgcn_s_setprio(1); \
    { \
        _Pragma("unroll") for (int kk = 0; kk < 2; ++kk) \
        _Pragma("unroll") for (int mi = 0; mi < 4; ++mi) \
        _Pragma("unroll") for (int ni = 0; ni < 2; ++ni) \
            acc[AOFF + mi][NIB + ni] = __builtin_amdgcn_mfma_f32_16x16x32_bf16( \
                AF[mi][kk], BF[ni][kk], acc[AOFF + mi][NIB + ni], 0, 0, 0); \
    } \
    __builtin_amdgcn_s_setprio(0);

// One K-tile t: consume CA/CB; stage KN -> NA/NB; prefetch-read t+1 frags from NA/NB.
#define TILE(CA, CB, NA, NB, KN) \
    /* ph1: read bA(t); stage whole t+1; wait (bA + any leftovers); aL x bA */ \
    RD_BA(CB); \
    stageA(NA, KN); stageB(NB, KN); \
    LGKM0(); \
    MFMA16(0, aL, bA, 0); \
    /* ph2: read aH(t); aL x bB (operands >=1 phase old, no wait) */ \
    RD_AH(CA); \
    MFMA16(0, aL, bB, 2); \
    /* ph3: stages visible; read aL(t+1); wait aH; aH x bB */ \
    VM0BAR(); \
    RD_AL(NA); \
    LGKM8(); \
    MFMA16(4, aH, bB, 2); \
    /* ph4: read bB(t+1); aH x bA (no wait); end barrier frees CA/CB */ \
    RD_BB(NB); \
    MFMA16(4, aH, bA, 0); \
    ENDBAR();

__global__ __launch_bounds__(512, 2) void gemm8p_kernel(
        const __hip_bfloat16* __restrict__ Xb,
        const __hip_bfloat16* __restrict__ Wb,
        float* __restrict__ C) {
    __shared__ alignas(16) char smem[131072];
    char* const ldsA = smem;            // [2][256 rows][64 bf16 = 128B]
    char* const ldsB = smem + 65536;

    const int tid  = threadIdx.x;
    const int lane = tid & 63;
    const int wave = tid >> 6;
    const int wr   = wave >> 2;     // 0..1  (M half)
    const int wc   = wave & 3;      // 0..3  (N quarter)
    const int l15  = lane & 15;
    const int lrow = lane >> 3;     // staging row-in-chunk
    const int ssw  = (((lane & 7) ^ lrow) << 4);   // pre-swizzled source col (bytes)

    // XCD-bijective swizzle (grid = 688, 688 % 8 == 0)
    unsigned bid = blockIdx.x;
    unsigned per = gridDim.x >> 3;               // 86
    unsigned swz = (bid & 7u) * per + (bid >> 3);
    const int tn = (int)(swz % (N_OUT / BN));    // 43
    const int tm = (int)(swz / (N_OUT / BN));    // 16
    const int m0 = tm * BM;
    const int n0 = tn * BN;

    // swizzled read column (bytes within a 128B row); kk toggles bit 6
    const int colswz = (((lane >> 4) << 4) ^ ((lane & 7) << 4));

    f32x4 acc[8][4];
#pragma unroll
    for (int i = 0; i < 8; ++i)
#pragma unroll
        for (int j = 0; j < 4; ++j) {
            f32x4 z = {0.f, 0.f, 0.f, 0.f};
            acc[i][j] = z;
        }
    bf16x8 aL[4][2], aH[4][2], bA[2][2], bB[2][2];

    // stage a full 32KB tile (4 x global_load_lds/thread, 8 rows per chunk)
    auto stageA = [&](char* dstTile, int kt) {
#pragma unroll
        for (int j = 0; j < 4; ++j) {
            int rb = (wave * 4 + j) * 8;
            const char* g = (const char*)Xb + ((size_t)(m0 + rb + lrow) * K_IN) * 2
                            + (size_t)kt * 128 + ssw;
            async_copy16(g, dstTile + rb * 128);
        }
    };
    auto stageB = [&](char* dstTile, int kt) {
#pragma unroll
        for (int j = 0; j < 4; ++j) {
            int rb = (wave * 4 + j) * 8;
            const char* g = (const char*)Wb + ((size_t)(n0 + rb + lrow) * K_IN) * 2
                            + (size_t)kt * 128 + ssw;
            async_copy16(g, dstTile + rb * 128);
        }
    };
    auto readA = [&](char* tile, int mi8, int kk) -> bf16x8 {
        return *(const bf16x8*)(tile + (wr * 128 + mi8 * 16 + l15) * 128 + (colswz ^ (kk << 6)));
    };
    auto readB = [&](char* tile, int ni4, int kk) -> bf16x8 {
        return *(const bf16x8*)(tile + (wc * 64 + ni4 * 16 + l15) * 128 + (colswz ^ (kk << 6)));
    };

    char* const A0 = ldsA;   char* const A1 = ldsA + 32768;
    char* const B0 = ldsB;   char* const B1 = ldsB + 32768;

    // ---- prologue: stage tile0 -> buf0; make visible; pre-read aL(t0), bB(t0)
    //      (the frags ph3/ph4 of a previous tile would have read) ----
    stageA(A0, 0); stageB(B0, 0);
    VM0BAR();
    RD_AL(A0); RD_BB(B0);

    for (int i = 0; i < KTILES / 2; ++i) {
        const int k1 = (2 * i + 1) & (KTILES - 1);
        const int k2 = (2 * i + 2) & (KTILES - 1);   // wraps on last iter: dead ops, harmless
        TILE(A0, B0, A1, B1, k1)   // consume buf0, stage k1 -> buf1
        TILE(A1, B1, A0, B0, k2)   // consume buf1, stage k2 -> buf0
    }

    // ---- epilogue: D layout col=lane&15, row=(lane>>4)*4+e ----
    const int r4 = (lane >> 4) << 2;
#pragma unroll
    for (int mi = 0; mi < 8; ++mi)
#pragma unroll
        for (int ni = 0; ni < 4; ++ni)
#pragma unroll
            for (int e = 0; e < 4; ++e) {
                int row = m0 + wr * 128 + mi * 16 + r4 + e;
                int col = n0 + wc * 64 + ni * 16 + l15;
                C[(size_t)row * N_OUT + col] = acc[mi][ni][e];
            }
}

extern "C" void kernel_launch(void* const* d_in, const int* in_sizes, int n_in,
                              void* d_out, int out_size, void* d_ws, size_t ws_size,
                              hipStream_t stream) {
    const float* x   = (const float*)d_in[0];
    const int*   wq  = (const int*)d_in[1];
    const float* snz = (const float*)d_in[2];
    float* out = (float*)d_out;

    __hip_bfloat16* Xb = (__hip_bfloat16*)d_ws;                                        // 32 MB
    __hip_bfloat16* Wb = (__hip_bfloat16*)((char*)d_ws + (size_t)M_TOKENS * K_IN * 2); // 86 MB

    cast_x_kernel<<<(M_TOKENS * (size_t)K_IN) / 8 / 256, 256, 0, stream>>>(x, Xb);
    dequant_kernel<<<((size_t)N_OUT * K_IN) / 8 / 256, 256, 0, stream>>>(wq, snz, Wb);
    gemm8p_kernel<<<(M_TOKENS / BM) * (N_OUT / BN), 512, 0, stream>>>(Xb, Wb, out);
}

// Round 10
// 597.798 us; speedup vs baseline: 1.3764x; 1.3764x over previous
//
#include <hip/hip_runtime.h>
#include <hip/hip_bf16.h>

#define M_TOKENS 4096
#define K_IN     4096
#define N_OUT    11008

#define BM 256
#define BN 256
#define BK 64
#define KTILES (K_IN / BK)   // 64

typedef __bf16 bf16x8 __attribute__((ext_vector_type(8)));
typedef float  f32x4  __attribute__((ext_vector_type(4)));
typedef float  f32x16 __attribute__((ext_vector_type(16)));

__device__ __forceinline__ void async_copy16(const void* g, void* l) {
    __builtin_amdgcn_global_load_lds(
        (const __attribute__((address_space(1))) void*)g,
        (__attribute__((address_space(3))) void*)l, 16, 0, 0);
}

// ---- x fp32 -> bf16 cast, 8 elems/thread ----
__global__ __launch_bounds__(256) void cast_x_kernel(const float* __restrict__ x,
                                                     __hip_bfloat16* __restrict__ xb) {
    size_t idx = (size_t)blockIdx.x * 256 + threadIdx.x;
    const float4* xf = reinterpret_cast<const float4*>(x) + idx * 2;
    float4 a = xf[0], b = xf[1];
    float v[8] = {a.x, a.y, a.z, a.w, b.x, b.y, b.z, b.w};
    alignas(16) __hip_bfloat16 t[8];
#pragma unroll
    for (int j = 0; j < 8; ++j) t[j] = __float2bfloat16(v[j]);
    *reinterpret_cast<uint4*>(xb + idx * 8) = *reinterpret_cast<const uint4*>(t);
}

// ---- int4-code dequant: wq[n,k] int32 -> wb[n,k] bf16 (B^T layout), 8 k/thread ----
__global__ __launch_bounds__(256) void dequant_kernel(const int* __restrict__ wq,
                                                      const float* __restrict__ snz,
                                                      __hip_bfloat16* __restrict__ wb) {
    size_t idx = (size_t)blockIdx.x * 256 + threadIdx.x;   // n*(K/8) + k8
    int n  = (int)(idx >> 9);         // K_IN/8 = 512
    int k8 = (int)(idx & 511);
    int g  = k8 >> 4;                 // (k8*8)/128
    const float* sz = snz + ((size_t)g * N_OUT + n) * 2;
    float scale = sz[0], zero = sz[1];
    const int4* q4 = reinterpret_cast<const int4*>(wq + (size_t)n * K_IN + (size_t)k8 * 8);
    int4 qa = q4[0], qb = q4[1];
    int q[8] = {qa.x, qa.y, qa.z, qa.w, qb.x, qb.y, qb.z, qb.w};
    alignas(16) __hip_bfloat16 t[8];
#pragma unroll
    for (int j = 0; j < 8; ++j)
        t[j] = __float2bfloat16((float)(q[j] - 8) * scale + zero);
    *reinterpret_cast<uint4*>(wb + idx * 8) = *reinterpret_cast<const uint4*>(t);
}

// ====== 256x256 bf16 GEMM — B-direct-to-register + 32x32x16 MFMA ======
// 7 schedule variants all hit the same ~4900 cyc/K-tile wall: LDS pipe (192KB
// reads + 64KB writes, 3x amplification) serializes against MFMA. This kernel
// REMOVES LDS traffic instead of rescheduling it:
//   - B fragments load straight global->register (16B/lane contiguous, L2/L3
//     resident; x2 wr-duplication = 64KB/tile/CU on the VMEM pipe)
//   - LDS holds only A (global_load_lds, double-buffered, 64KB)
//   - 32x32x16 MFMA: 4-VGPR frags (doubled B set fits), +20% matrix-pipe rate
// Sync: ONE vmcnt(8)+barrier per tile (drains the 4 A-stages only; SCB after
// stageA pins them oldest in the FIFO ahead of the 8 B-loads). All other
// ordering is compiler data-deps with precise auto-waitcnts (m97 mechanism).
// Layouts: C/D col=lane&31,row=(reg&3)+8*(reg>>2)+4*(lane>>5) [m74/m101];
// A row=lane&31,k=(lane>>5)*8+j (symmetric to m89-verified 16x16 mapping).

#define SCB()  __builtin_amdgcn_sched_barrier(0)
#define VM8BAR() { SCB(); asm volatile("s_waitcnt vmcnt(8)" ::: "memory"); \
                   __builtin_amdgcn_s_barrier(); SCB(); }

#define RDA(AF, T, KS) \
    _Pragma("unroll") for (int mf = 0; mf < 4; ++mf) AF[mf] = readA(T, mf, KS);

#define LOADB(DST, KT, HALF) \
    _Pragma("unroll") for (int nf = 0; nf < 2; ++nf) \
    _Pragma("unroll") for (int j = 0; j < 2; ++j) { \
        const int ks = (HALF) * 2 + j; \
        const char* g = (const char*)Wb \
            + (size_t)(n0 + wc * 64 + nf * 32 + l31) * (K_IN * 2) \
            + (size_t)(KT) * 128 + ks * 32 + kb16; \
        DST[nf][ks] = *(const bf16x8*)g; \
    }

#define MM(AF, BC, KS) \
    __builtin_amdgcn_s_setprio(1); \
    { \
        _Pragma("unroll") for (int mf = 0; mf < 4; ++mf) \
        _Pragma("unroll") for (int nf = 0; nf < 2; ++nf) \
            acc[mf][nf] = __builtin_amdgcn_mfma_f32_32x32x16_bf16( \
                AF[mf], BC[nf][KS], acc[mf][nf], 0, 0, 0); \
    } \
    __builtin_amdgcn_s_setprio(0);

// One K-tile: consume A from CUR + B from BC regs; stage A(KN)->ALT; load B(KN)->BN_.
#define TILE(CUR, ALT, BC, BN_, KN) \
    stageA(ALT, KN); \
    SCB();                      /* pin: 4 stages oldest in VMEM FIFO */ \
    LOADB(BN_, KN, 0); \
    RDA(aF1, CUR, 1); \
    MM(aF0, BC, 0); \
    RDA(aF0, CUR, 2); \
    MM(aF1, BC, 1); \
    LOADB(BN_, KN, 1); \
    RDA(aF1, CUR, 3); \
    MM(aF0, BC, 2); \
    MM(aF1, BC, 3); \
    VM8BAR();                   /* drain stages (8 B-loads may fly); ALT visible */ \
    RDA(aF0, ALT, 0);           /* next tile ks0, post-barrier */

__global__ __launch_bounds__(512, 2) void gemm_bd_kernel(
        const __hip_bfloat16* __restrict__ Xb,
        const __hip_bfloat16* __restrict__ Wb,
        float* __restrict__ C) {
    __shared__ alignas(16) char smem[65536];   // A only: 2 x [256 rows][128B]

    const int tid  = threadIdx.x;
    const int lane = tid & 63;
    const int wave = tid >> 6;
    const int wr   = wave >> 2;     // 0..1  (M half, 128 rows)
    const int wc   = wave & 3;      // 0..3  (N quarter, 64 cols)
    const int l31  = lane & 31;
    const int kb16 = ((lane >> 5) << 4);   // 16B k-group offset within 32B slice
    const int lrow = lane >> 3;     // staging row-in-chunk
    const int ssw  = (((lane & 7) ^ lrow) << 4);   // pre-swizzled source col (bytes)

    // XCD-bijective swizzle (grid = 688, 688 % 8 == 0)
    unsigned bid = blockIdx.x;
    unsigned per = gridDim.x >> 3;               // 86
    unsigned swz = (bid & 7u) * per + (bid >> 3);
    const int tn = (int)(swz % (N_OUT / BN));    // 43
    const int tm = (int)(swz / (N_OUT / BN));    // 16
    const int m0 = tm * BM;
    const int n0 = tn * BN;

    f32x16 acc[4][2];
#pragma unroll
    for (int i = 0; i < 4; ++i)
#pragma unroll
        for (int j = 0; j < 2; ++j)
#pragma unroll
            for (int e = 0; e < 16; ++e) acc[i][j][e] = 0.f;

    bf16x8 aF0[4], aF1[4], bX[2][4], bY[2][4];

    // stage a full 32KB A-tile (4 x global_load_lds/thread, 8 rows per chunk)
    auto stageA = [&](char* dstTile, int kt) {
#pragma unroll
        for (int j = 0; j < 4; ++j) {
            int rb = (wave * 4 + j) * 8;
            const char* g = (const char*)Xb + ((size_t)(m0 + rb + lrow) * K_IN) * 2
                            + (size_t)kt * 128 + ssw;
            async_copy16(g, dstTile + rb * 128);
        }
    };
    // A-frag: row = wr*128 + mf*32 + (lane&31); k-slice ks: 16B slot (ks*2+(lane>>5)) ^ (row&7)
    auto readA = [&](char* tile, int mf, int ks) -> bf16x8 {
        int row  = wr * 128 + mf * 32 + l31;
        int slot = (ks * 2 + (lane >> 5)) ^ (lane & 7);
        return *(const bf16x8*)(tile + row * 128 + slot * 16);
    };

    char* const A0 = smem;   char* const A1 = smem + 32768;

    // ---- prologue: stage A(t0); load B(t0); drain stages; pre-read ks0 ----
    stageA(A0, 0);
    SCB();
    LOADB(bX, 0, 0);
    LOADB(bX, 0, 1);
    VM8BAR();
    RDA(aF0, A0, 0);

    for (int i = 0; i < KTILES / 2; ++i) {
        const int k1 = (2 * i + 1) & (KTILES - 1);
        const int k2 = (2 * i + 2) & (KTILES - 1);   // wraps on last iter: dead ops, harmless
        TILE(A0, A1, bX, bY, k1)
        TILE(A1, A0, bY, bX, k2)
    }

    // ---- epilogue: 32x32 D layout col=lane&31, row=(e&3)+8*(e>>2)+4*(lane>>5) ----
    const int r4 = (lane >> 5) << 2;
#pragma unroll
    for (int mf = 0; mf < 4; ++mf)
#pragma unroll
        for (int nf = 0; nf < 2; ++nf)
#pragma unroll
            for (int e = 0; e < 16; ++e) {
                int row = m0 + wr * 128 + mf * 32 + (e & 3) + ((e >> 2) << 3) + r4;
                int col = n0 + wc * 64 + nf * 32 + l31;
                C[(size_t)row * N_OUT + col] = acc[mf][nf][e];
            }
}

extern "C" void kernel_launch(void* const* d_in, const int* in_sizes, int n_in,
                              void* d_out, int out_size, void* d_ws, size_t ws_size,
                              hipStream_t stream) {
    const float* x   = (const float*)d_in[0];
    const int*   wq  = (const int*)d_in[1];
    const float* snz = (const float*)d_in[2];
    float* out = (float*)d_out;

    __hip_bfloat16* Xb = (__hip_bfloat16*)d_ws;                                        // 32 MB
    __hip_bfloat16* Wb = (__hip_bfloat16*)((char*)d_ws + (size_t)M_TOKENS * K_IN * 2); // 86 MB

    cast_x_kernel<<<(M_TOKENS * (size_t)K_IN) / 8 / 256, 256, 0, stream>>>(x, Xb);
    dequant_kernel<<<((size_t)N_OUT * K_IN) / 8 / 256, 256, 0, stream>>>(wq, snz, Wb);
    gemm_bd_kernel<<<(M_TOKENS / BM) * (N_OUT / BN), 512, 0, stream>>>(Xb, Wb, out);
}